// Round 13
// baseline (870.940 us; speedup 1.0000x reference)
//
#include <hip/hip_runtime.h>
#include <hip/hip_bf16.h>
#include <math.h>

// Problem constants
constexpr int kB   = 2;
constexpr int kL   = 1024;
constexpr int kOBS = 64;
constexpr int kACT = 16;
constexpr int kC   = 1024;
constexpr int kH   = 16;
constexpr int kDH  = 64;
constexpr int kFF  = 4096;
constexpr int kNL  = 4;
constexpr int kRows = kB * kL;          // 2048
constexpr int kOE = 512, kAE = 256, kRE = 128, kTE = 128;

typedef _Float16 f16x8 __attribute__((ext_vector_type(8)));
typedef _Float16 f16x4 __attribute__((ext_vector_type(4)));
typedef float    f32x4 __attribute__((ext_vector_type(4)));

__device__ __forceinline__ unsigned short f2h(float x) {
    return __builtin_bit_cast(unsigned short, (_Float16)x);
}
__device__ __forceinline__ void gload_lds16(const void* g, void* l) {
    __builtin_amdgcn_global_load_lds(
        (const __attribute__((address_space(1))) unsigned int*)g,
        (__attribute__((address_space(3))) unsigned int*)l, 16, 0, 0);
}

// ---------------------------------------------------------------------------
// 1. Transition batchnorm stats
// ---------------------------------------------------------------------------
__global__ __launch_bounds__(256) void tran_stats_kernel(
    const float* __restrict__ obs, float* __restrict__ tm, float* __restrict__ tv)
{
    const int f = blockIdx.x;
    const int tid = threadIdx.x;
    float sum = 0.f, sq = 0.f;
    for (int r = tid; r < kRows; r += 256) {
        const int t = r & (kL - 1);
        float d = 0.f;
        if (t > 0) {
            const float cur  = obs[(size_t)r * kOBS + f];
            const float prev = obs[(size_t)(r - 1) * kOBS + f];
            d = cur - prev;
        }
        sum += d; sq += d * d;
    }
    for (int off = 32; off > 0; off >>= 1) {
        sum += __shfl_down(sum, off);
        sq  += __shfl_down(sq, off);
    }
    __shared__ float sa[4], sb[4];
    if ((tid & 63) == 0) { sa[tid >> 6] = sum; sb[tid >> 6] = sq; }
    __syncthreads();
    if (tid == 0) {
        const float ts = sa[0] + sa[1] + sa[2] + sa[3];
        const float tq = sb[0] + sb[1] + sb[2] + sb[3];
        const float m = ts / (float)kRows;
        tm[f] = m;
        tv[f] = tq / (float)kRows - m * m;
    }
}

// ---------------------------------------------------------------------------
// 2. Encoder (writes fp32 residual stream)
// ---------------------------------------------------------------------------
__global__ __launch_bounds__(256) void encode_kernel(
    const float* __restrict__ obs, const float* __restrict__ act, const float* __restrict__ rew,
    const float* __restrict__ obs_W, const float* __restrict__ obs_b,
    const float* __restrict__ act_W, const float* __restrict__ act_b,
    const float* __restrict__ rew_W, const float* __restrict__ rew_b,
    const float* __restrict__ tr_W,  const float* __restrict__ tr_b,
    const float* __restrict__ bn_g,  const float* __restrict__ bn_b,
    const float* __restrict__ tm,    const float* __restrict__ tv,
    float* __restrict__ enc)
{
    const int row = blockIdx.x;
    const int t = row & (kL - 1);
    const int tid = threadIdx.x;
    __shared__ float s_obs2[kOBS];
    __shared__ float s_tran[kOBS];
    __shared__ float s_act[kACT];
    __shared__ float s_rew;
    if (tid < kOBS) {
        const float cur  = obs[(size_t)row * kOBS + tid];
        const float prev = (t > 0) ? obs[(size_t)(row - 1) * kOBS + tid] : cur;
        s_obs2[tid] = prev;
        const float tr = cur - prev;
        s_tran[tid] = (tr - tm[tid]) * rsqrtf(tv[tid] + 1e-5f) * bn_g[tid] + bn_b[tid];
    } else if (tid < kOBS + kACT) {
        s_act[tid - kOBS] = act[(size_t)row * kACT + (tid - kOBS)];
    } else if (tid == kOBS + kACT) {
        s_rew = rew[row];
    }
    __syncthreads();
    float* er = enc + (size_t)row * kC;
    #pragma unroll
    for (int s = 0; s < 4; ++s) {
        const int c = tid + s * 256;
        float v;
        if (c < kOE) {
            v = obs_b[c];
            #pragma unroll
            for (int k = 0; k < kOBS; ++k) v += s_obs2[k] * obs_W[k * kOE + c];
        } else if (c < kOE + kAE) {
            const int cc = c - kOE;
            v = act_b[cc];
            #pragma unroll
            for (int k = 0; k < kACT; ++k) v += s_act[k] * act_W[k * kAE + cc];
        } else if (c < kOE + kAE + kRE) {
            const int cc = c - (kOE + kAE);
            v = s_rew * rew_W[cc] + rew_b[cc];
        } else {
            const int cc = c - (kOE + kAE + kRE);
            v = tr_b[cc];
            #pragma unroll
            for (int k = 0; k < kOBS; ++k) v += s_tran[k] * tr_W[k * kTE + cc];
        }
        er[c] = v;
    }
}

// ---------------------------------------------------------------------------
// 3. LayerNorm: fp32 in -> fp16 out
// ---------------------------------------------------------------------------
__global__ __launch_bounds__(256) void ln_kernel(
    const float* __restrict__ x, const float* __restrict__ w,
    const float* __restrict__ b, unsigned short* __restrict__ out)
{
    const int row = blockIdx.x;
    const int tid = threadIdx.x;
    const float4 xv = *reinterpret_cast<const float4*>(&x[(size_t)row * kC + tid * 4]);
    float s = xv.x + xv.y + xv.z + xv.w;
    float q = xv.x * xv.x + xv.y * xv.y + xv.z * xv.z + xv.w * xv.w;
    for (int off = 32; off > 0; off >>= 1) {
        s += __shfl_down(s, off);
        q += __shfl_down(q, off);
    }
    __shared__ float sa[4], sb[4];
    if ((tid & 63) == 0) { sa[tid >> 6] = s; sb[tid >> 6] = q; }
    __syncthreads();
    const float ts = sa[0] + sa[1] + sa[2] + sa[3];
    const float tq = sb[0] + sb[1] + sb[2] + sb[3];
    const float mean = ts * (1.f / kC);
    const float var  = tq * (1.f / kC) - mean * mean;
    const float rstd = rsqrtf(var + 1e-5f);
    const float4 wv = *reinterpret_cast<const float4*>(&w[tid * 4]);
    const float4 bv = *reinterpret_cast<const float4*>(&b[tid * 4]);
    ushort4 o;
    o.x = f2h((xv.x - mean) * rstd * wv.x + bv.x);
    o.y = f2h((xv.y - mean) * rstd * wv.y + bv.y);
    o.z = f2h((xv.z - mean) * rstd * wv.z + bv.z);
    o.w = f2h((xv.w - mean) * rstd * wv.w + bv.w);
    *reinterpret_cast<ushort4*>(&out[(size_t)row * kC + tid * 4]) = o;
}

// ---------------------------------------------------------------------------
// 4a. Per-layer weight convert+transpose, single launch (3072 tiles).
// ---------------------------------------------------------------------------
__device__ __forceinline__ void convT_tile(
    const float* __restrict__ W, unsigned short* __restrict__ WT,
    int K, int N, int k0, int n0, int tid)
{
    __shared__ unsigned short t[64][68];
    const int r = tid >> 4, c4 = (tid & 15) * 4;
    #pragma unroll
    for (int s = 0; s < 4; ++s) {
        const int rr = r + s * 16;
        const float4 v = *reinterpret_cast<const float4*>(&W[(size_t)(k0 + rr) * N + n0 + c4]);
        t[rr][c4 + 0] = f2h(v.x);
        t[rr][c4 + 1] = f2h(v.y);
        t[rr][c4 + 2] = f2h(v.z);
        t[rr][c4 + 3] = f2h(v.w);
    }
    __syncthreads();
    #pragma unroll
    for (int s = 0; s < 4; ++s) {
        const int rn = r + s * 16;
        ushort4 o;
        o.x = t[c4 + 0][rn];
        o.y = t[c4 + 1][rn];
        o.z = t[c4 + 2][rn];
        o.w = t[c4 + 3][rn];
        *reinterpret_cast<ushort4*>(&WT[(size_t)(n0 + rn) * K + k0 + c4]) = o;
    }
}

__global__ __launch_bounds__(256) void convert_layer_kernel(
    const float* __restrict__ qW, const float* __restrict__ oW,
    const float* __restrict__ fW, const float* __restrict__ pW,
    unsigned short* __restrict__ qWT, unsigned short* __restrict__ oWT,
    unsigned short* __restrict__ fWT, unsigned short* __restrict__ pWT)
{
    int bid = blockIdx.x;                    // 3072 tiles total
    const int tid = threadIdx.x;
    if (bid < 768)  {                        // qW: K=1024, N=3072 (48 n-tiles)
        convT_tile(qW, qWT, 1024, 3072, (bid / 48) * 64, (bid % 48) * 64, tid);
    } else if (bid < 1024) {                 // oW: 1024x1024 (16)
        bid -= 768;
        convT_tile(oW, oWT, 1024, 1024, (bid / 16) * 64, (bid % 16) * 64, tid);
    } else if (bid < 2048) {                 // fW: K=1024, N=4096 (64)
        bid -= 1024;
        convT_tile(fW, fWT, 1024, 4096, (bid / 64) * 64, (bid % 64) * 64, tid);
    } else {                                 // pW: K=4096, N=1024 (16)
        bid -= 2048;
        convT_tile(pW, pWT, 4096, 1024, (bid / 16) * 64, (bid % 16) * 64, tid);
    }
}

// ---------------------------------------------------------------------------
// 4b. fp16 MFMA GEMM, 128x128 tile, BK=32, 3-buffer counted-vmcnt pipeline
//     (unchanged from round 12). XCD-aware block swizzle.
//     MODE 0: f32 out (+RES/RELU). MODE 1: f16 out. MODE 2: qkv special.
//     MODE 4: split-K atomicAdd into Cf.
// ---------------------------------------------------------------------------
template<int RELU, int RES, int MODE>
__global__ __launch_bounds__(256) void gemm_f16_kernel(
    const unsigned short* __restrict__ A,   // [M][K] fp16
    const unsigned short* __restrict__ BT,  // [N][K] fp16
    const float* __restrict__ bias,
    float* __restrict__ Cf, unsigned short* __restrict__ Ch,
    unsigned short* __restrict__ Cv,
    int M, int N, int K)
{
    __shared__ __align__(16) unsigned short As[3][128 * 32];   // 3 x 8 KB
    __shared__ __align__(16) unsigned short Bs[3][128 * 32];   // 3 x 8 KB
    const int tid = threadIdx.x;
    const int lane = tid & 63;
    const int wv   = tid >> 6;
    const int wr = wv >> 1, wc = wv & 1;

    // XCD-aware swizzle (bijective: all our grids are divisible by 8)
    const int nx  = gridDim.x;
    const int nxy = gridDim.x * gridDim.y;
    int flat = blockIdx.x + nx * blockIdx.y + nxy * blockIdx.z;
    const int cpx = (nxy * gridDim.z) >> 3;
    flat = (flat & 7) * cpx + (flat >> 3);
    const int bx = flat % nx;
    const int by = (flat / nx) % gridDim.y;
    const int bz = flat / nxy;

    const int bm = by * 128;
    const int bn = bx * 128;
    const int ksz  = K / gridDim.z;
    const int kbeg = bz * ksz;
    const int kend = kbeg + ksz;

    // staging: row stride 32 halves = 64 B = 4 slots of 16 B.
    const int grow = tid >> 2;                  // 0..63
    const int gs   = (tid & 3) ^ ((tid >> 3) & 3);

    const int fr = lane & 15;
    const int kb = lane >> 4;                   // 0..3

    auto stage = [&](int k0, int buf) {
        gload_lds16(A  + (size_t)(bm + grow) * K + k0 + gs * 8,
                    (char*)&As[buf][0] + wv * 1024);
        gload_lds16(A  + (size_t)(bm + 64 + grow) * K + k0 + gs * 8,
                    (char*)&As[buf][0] + 4096 + wv * 1024);
        gload_lds16(BT + (size_t)(bn + grow) * K + k0 + gs * 8,
                    (char*)&Bs[buf][0] + wv * 1024);
        gload_lds16(BT + (size_t)(bn + 64 + grow) * K + k0 + gs * 8,
                    (char*)&Bs[buf][0] + 4096 + wv * 1024);
    };

    f32x4 acc[4][4] = {};

    // prologue: 2 stages in flight (8 vmem ops/wave)
    stage(kbeg, 0);
    if (kbeg + 32 < kend) stage(kbeg + 32, 1);
    int cur = 0;
    for (int k0 = kbeg; k0 < kend; k0 += 32) {
        if (k0 + 32 < kend) {
            asm volatile("s_waitcnt vmcnt(4)" ::: "memory");
        } else {
            asm volatile("s_waitcnt vmcnt(0)" ::: "memory");
        }
        asm volatile("s_waitcnt lgkmcnt(0)" ::: "memory");
        __builtin_amdgcn_sched_barrier(0);
        __builtin_amdgcn_s_barrier();
        __builtin_amdgcn_sched_barrier(0);

        f16x8 a[4], b[4];
        #pragma unroll
        for (int m = 0; m < 4; ++m) {
            const int row = wr * 64 + m * 16 + fr;
            a[m] = *reinterpret_cast<const f16x8*>(
                &As[cur][row * 32 + ((kb ^ ((row >> 1) & 3)) * 8)]);
        }
        #pragma unroll
        for (int n = 0; n < 4; ++n) {
            const int row = wc * 64 + n * 16 + fr;
            b[n] = *reinterpret_cast<const f16x8*>(
                &Bs[cur][row * 32 + ((kb ^ ((row >> 1) & 3)) * 8)]);
        }
        if (k0 + 64 < kend) {
            int sb = cur + 2; if (sb >= 3) sb -= 3;
            stage(k0 + 64, sb);
        }
        #pragma unroll
        for (int m = 0; m < 4; ++m)
            #pragma unroll
            for (int n = 0; n < 4; ++n)
                acc[m][n] = __builtin_amdgcn_mfma_f32_16x16x32_f16(
                    a[m], b[n], acc[m][n], 0, 0, 0);

        ++cur; if (cur >= 3) cur = 0;
    }

    const int fq = lane >> 4;
    if (MODE == 4) {                 // split-K atomic accumulate (RES via x)
        const bool addb = (bz == 0);
        #pragma unroll
        for (int n = 0; n < 4; ++n) {
            const int c = bn + wc * 64 + n * 16 + fr;
            const float bv = addb ? bias[c] : 0.f;
            #pragma unroll
            for (int m = 0; m < 4; ++m) {
                #pragma unroll
                for (int j = 0; j < 4; ++j) {
                    const int r = bm + wr * 64 + m * 16 + fq * 4 + j;
                    atomicAdd(&Cf[(size_t)r * N + c], acc[m][n][j] + bv);
                }
            }
        }
        return;
    }
    if (MODE == 2) {
        if (bn < 2 * kC) {          // Q,K region -> qk f16 [row][2048]
            #pragma unroll
            for (int n = 0; n < 4; ++n) {
                const int c = bn + wc * 64 + n * 16 + fr;
                const float bv = bias[c];
                #pragma unroll
                for (int m = 0; m < 4; ++m) {
                    #pragma unroll
                    for (int j = 0; j < 4; ++j) {
                        const int r = bm + wr * 64 + m * 16 + fq * 4 + j;
                        Ch[(size_t)r * (2 * kC) + c] = f2h(acc[m][n][j] + bv);
                    }
                }
            }
        } else {                    // V region -> vt[b][h][d][t] f16
            #pragma unroll
            for (int n = 0; n < 4; ++n) {
                const int c  = bn + wc * 64 + n * 16 + fr;
                const int cc = c - 2 * kC;
                const int hh = cc >> 6, dd = cc & 63;
                const float bv = bias[c];
                #pragma unroll
                for (int m = 0; m < 4; ++m) {
                    const int rr = bm + wr * 64 + m * 16 + fq * 4;
                    const int bb = rr >> 10, t0 = rr & 1023;
                    f16x4 pk;
                    #pragma unroll
                    for (int j = 0; j < 4; ++j) pk[j] = (_Float16)(acc[m][n][j] + bv);
                    *reinterpret_cast<f16x4*>(
                        &Cv[((size_t)(bb * kH + hh) * kDH + dd) * kL + t0]) = pk;
                }
            }
        }
        return;
    }
    #pragma unroll
    for (int n = 0; n < 4; ++n) {
        const int c = bn + wc * 64 + n * 16 + fr;
        const float bv = bias[c];
        #pragma unroll
        for (int m = 0; m < 4; ++m) {
            #pragma unroll
            for (int j = 0; j < 4; ++j) {
                const int r = bm + wr * 64 + m * 16 + fq * 4 + j;
                float v = acc[m][n][j] + bv;
                if (RES)  v += Cf[(size_t)r * N + c];
                if (RELU) v = fmaxf(v, 0.f);
                if (MODE == 1) Ch[(size_t)r * N + c] = f2h(v);
                else           Cf[(size_t)r * N + c] = v;
            }
        }
    }
}

// ---------------------------------------------------------------------------
// 5. MFMA flash attention, NO K/V/Q LDS staging: per-head K/V is 256 KB ->
//    L2-resident, and in the swapped layout every MFMA fragment is a
//    contiguous 16 B global read (4-lane groups cover 64 B runs). Inner loop
//    is barrier-free: only wave-private P staging in LDS (same-wave in-order
//    DS write->read). 8 KB LDS total.
// ---------------------------------------------------------------------------
__device__ __forceinline__ int swz(int row, int slot) {
    return row * 64 + ((slot ^ (row & 7)) * 8);   // ushort index, 16B-aligned
}

__global__ __launch_bounds__(256) void attn_mfma_kernel(
    const unsigned short* __restrict__ qk,   // [2048][2048] f16 (Q | K)
    const unsigned short* __restrict__ vt,   // [2][16][64][1024] f16  V^T
    unsigned short* __restrict__ o)          // [2048][1024] f16
{
    const int bid = blockIdx.x;            // 512 blocks
    const int bh  = bid & 31;
    const int qb  = ((bid >> 5) + bh) & 15;   // shear: balance causal work
    const int b   = bh >> 4;
    const int h   = bh & 15;
    const int tid  = threadIdx.x;
    const int lane = tid & 63;
    const int wv   = tid >> 6;
    const int fr = lane & 15;              // q index within wave
    const int g  = lane >> 4;              // k-group

    __shared__ __align__(16) unsigned short Ps[64 * 64];   // 8 KB, wave-private rows

    const int qlo = qb * 64;
    const int qg_row = qlo + wv * 16 + fr;

    // Q fragments direct from global, prescaled by 1/8 (exact in f16)
    f16x8 qfrag[2];
    {
        const unsigned short* qg = &qk[(size_t)(b * kL + qg_row) * (2 * kC) + h * kDH];
        #pragma unroll
        for (int kf = 0; kf < 2; ++kf) {
            f16x8 v = *reinterpret_cast<const f16x8*>(&qg[(kf * 4 + g) * 8]);
            #pragma unroll
            for (int i = 0; i < 8; ++i) v[i] *= (_Float16)0.125f;
            qfrag[kf] = v;
        }
    }

    float m = -INFINITY, l = 0.f;
    f32x4 acc_o[4] = {};

    const unsigned short* kbase = &qk[(size_t)(b * kL) * (2 * kC) + kC + h * kDH];
    const unsigned short* vbase = &vt[(size_t)(b * kH + h) * kDH * kL];

    for (int k0 = 0; k0 <= qlo; k0 += 64) {
        // QK^T (swapped): K fragments direct from global (L2-hit)
        f32x4 acc_s[4] = {};
        #pragma unroll
        for (int kf = 0; kf < 2; ++kf) {
            #pragma unroll
            for (int n = 0; n < 4; ++n) {
                const f16x8 kfr = *reinterpret_cast<const f16x8*>(
                    &kbase[(size_t)(k0 + n * 16 + fr) * (2 * kC) + (kf * 4 + g) * 8]);
                acc_s[n] = __builtin_amdgcn_mfma_f32_16x16x32_f16(kfr, qfrag[kf], acc_s[n], 0, 0, 0);
            }
        }

        // causal mask (diagonal tile only)
        if (k0 == qlo) {
            #pragma unroll
            for (int n = 0; n < 4; ++n)
                #pragma unroll
                for (int j = 0; j < 4; ++j)
                    if (k0 + n * 16 + g * 4 + j > qg_row) acc_s[n][j] = -INFINITY;
        }

        // online softmax (row q lives in 4 lanes: reduce via xor 16,32)
        float mx = -INFINITY;
        #pragma unroll
        for (int n = 0; n < 4; ++n)
            #pragma unroll
            for (int j = 0; j < 4; ++j) mx = fmaxf(mx, acc_s[n][j]);
        mx = fmaxf(mx, __shfl_xor(mx, 16));
        mx = fmaxf(mx, __shfl_xor(mx, 32));
        const float mn  = fmaxf(m, mx);
        const float fac = __expf(m - mn);
        float p[4][4];
        float psum = 0.f;
        #pragma unroll
        for (int n = 0; n < 4; ++n)
            #pragma unroll
            for (int j = 0; j < 4; ++j) { p[n][j] = __expf(acc_s[n][j] - mn); psum += p[n][j]; }
        psum += __shfl_xor(psum, 16);
        psum += __shfl_xor(psum, 32);
        l = l * fac + psum;
        m = mn;
        #pragma unroll
        for (int dt = 0; dt < 4; ++dt)
            #pragma unroll
            for (int j = 0; j < 4; ++j) acc_o[dt][j] *= fac;

        // P -> LDS f16 (wave-private rows; same-wave in-order DS, no barrier)
        #pragma unroll
        for (int n = 0; n < 4; ++n) {
            f16x4 pk;
            #pragma unroll
            for (int j = 0; j < 4; ++j) pk[j] = (_Float16)p[n][j];
            *reinterpret_cast<f16x4*>(&Ps[swz(wv * 16 + fr, 2 * n + (g >> 1)) + (g & 1) * 4]) = pk;
        }

        // PV: V^T fragments direct from global (L2-hit)
        #pragma unroll
        for (int kf = 0; kf < 2; ++kf) {
            const f16x8 pf = *reinterpret_cast<const f16x8*>(&Ps[swz(wv * 16 + fr, kf * 4 + g)]);
            #pragma unroll
            for (int dt = 0; dt < 4; ++dt) {
                const f16x8 vf = *reinterpret_cast<const f16x8*>(
                    &vbase[(size_t)(dt * 16 + fr) * kL + k0 + (kf * 4 + g) * 8]);
                acc_o[dt] = __builtin_amdgcn_mfma_f32_16x16x32_f16(vf, pf, acc_o[dt], 0, 0, 0);
            }
        }
    }

    const float rl = 1.f / l;
    unsigned short* ob = &o[(size_t)(b * kL + qg_row) * kC + h * kDH];
    #pragma unroll
    for (int dt = 0; dt < 4; ++dt) {
        f16x4 pk;
        #pragma unroll
        for (int j = 0; j < 4; ++j) pk[j] = (_Float16)(acc_o[dt][j] * rl);
        *reinterpret_cast<f16x4*>(&ob[dt * 16 + g * 4]) = pk;
    }
}

// ---------------------------------------------------------------------------
// 6. Final tanh (in place on d_out)
// ---------------------------------------------------------------------------
__global__ __launch_bounds__(256) void tanh_kernel(float* __restrict__ x)
{
    const size_t i = ((size_t)blockIdx.x * 256 + threadIdx.x) * 4;
    float4 v = *reinterpret_cast<float4*>(&x[i]);
    v.x = tanhf(v.x); v.y = tanhf(v.y); v.z = tanhf(v.z); v.w = tanhf(v.w);
    *reinterpret_cast<float4*>(&x[i]) = v;
}

// ---------------------------------------------------------------------------
extern "C" void kernel_launch(void* const* d_in, const int* in_sizes, int n_in,
                              void* d_out, int out_size, void* d_ws, size_t ws_size,
                              hipStream_t stream)
{
    (void)in_sizes; (void)n_in; (void)out_size; (void)ws_size;
    const float* obs    = (const float*)d_in[0];
    const float* act    = (const float*)d_in[1];
    const float* rew    = (const float*)d_in[2];
    const float* obs_W  = (const float*)d_in[3];
    const float* obs_b  = (const float*)d_in[4];
    const float* act_W  = (const float*)d_in[5];
    const float* act_b  = (const float*)d_in[6];
    const float* rew_W  = (const float*)d_in[7];
    const float* rew_b  = (const float*)d_in[8];
    const float* tr_W   = (const float*)d_in[9];
    const float* tr_b   = (const float*)d_in[10];
    const float* bn_g   = (const float*)d_in[11];
    const float* bn_b   = (const float*)d_in[12];
    const float* ln1_w  = (const float*)d_in[13];
    const float* ln1_b  = (const float*)d_in[14];
    const float* qkv_W  = (const float*)d_in[15];
    const float* qkv_b  = (const float*)d_in[16];
    const float* out_W  = (const float*)d_in[17];
    const float* out_b  = (const float*)d_in[18];
    const float* ln2_w  = (const float*)d_in[19];
    const float* ln2_b  = (const float*)d_in[20];
    const float* fc_W   = (const float*)d_in[21];
    const float* fc_b   = (const float*)d_in[22];
    const float* pj_W   = (const float*)d_in[23];
    const float* pj_b   = (const float*)d_in[24];

    float* x  = (float*)d_out;                     // fp32 residual stream
    float* ws = (float*)d_ws;
    float* tm   = ws;                              // 64
    float* tv   = ws + 64;                         // 64
    unsigned short* wbuf  = (unsigned short*)(ws + 128);  // 12.58M f16 weights
    unsigned short* h_hf  = wbuf + 12582912;       // 2048*1024
    unsigned short* ao_hf = h_hf + (size_t)kRows * kC;    // 2048*1024
    unsigned short* ff_hf = ao_hf + (size_t)kRows * kC;   // 2048*4096
    unsigned short* qk_hf = ff_hf + (size_t)kRows * kFF;  // 2048*2048
    unsigned short* vt_hf = qk_hf + (size_t)kRows * 2 * kC; // 2*16*64*1024
    unsigned short* qWT = wbuf;                    // [3072][1024]
    unsigned short* oWT = qWT + 3 * kC * kC;       // [1024][1024]
    unsigned short* fWT = oWT + kC * kC;           // [4096][1024]
    unsigned short* pWT = fWT + kC * kFF;          // [1024][4096]

    tran_stats_kernel<<<kOBS, 256, 0, stream>>>(obs, tm, tv);
    encode_kernel<<<kRows, 256, 0, stream>>>(obs, act, rew,
        obs_W, obs_b, act_W, act_b, rew_W, rew_b, tr_W, tr_b, bn_g, bn_b, tm, tv, x);

    for (int lyr = 0; lyr < kNL; ++lyr) {
        const float* qW = qkv_W + (size_t)lyr * kC * 3 * kC;
        const float* qB = qkv_b + (size_t)lyr * 3 * kC;
        const float* oW = out_W + (size_t)lyr * kC * kC;
        const float* oB = out_b + (size_t)lyr * kC;
        const float* fW = fc_W + (size_t)lyr * kC * kFF;
        const float* fB = fc_b + (size_t)lyr * kFF;
        const float* pW = pj_W + (size_t)lyr * kFF * kC;
        const float* pB = pj_b + (size_t)lyr * kC;

        convert_layer_kernel<<<3072, 256, 0, stream>>>(
            qW, oW, fW, pW, qWT, oWT, fWT, pWT);

        ln_kernel<<<kRows, 256, 0, stream>>>(x, ln1_w + lyr * kC, ln1_b + lyr * kC, h_hf);
        gemm_f16_kernel<0,0,2><<<dim3(3 * kC / 128, kRows / 128), 256, 0, stream>>>(
            h_hf, qWT, qB, nullptr, qk_hf, vt_hf, kRows, 3 * kC, kC);
        attn_mfma_kernel<<<dim3(512), 256, 0, stream>>>(qk_hf, vt_hf, ao_hf);
        // out projection: split-K=4, atomic accumulate into residual stream
        gemm_f16_kernel<0,0,4><<<dim3(kC / 128, kRows / 128, 4), 256, 0, stream>>>(
            ao_hf, oWT, oB, x, nullptr, nullptr, kRows, kC, kC);
        ln_kernel<<<kRows, 256, 0, stream>>>(x, ln2_w + lyr * kC, ln2_b + lyr * kC, h_hf);
        gemm_f16_kernel<1,0,1><<<dim3(kFF / 128, kRows / 128), 256, 0, stream>>>(
            h_hf, fWT, fB, nullptr, ff_hf, nullptr, kRows, kFF, kC);
        // pj projection: split-K=8, atomic accumulate into residual stream
        gemm_f16_kernel<0,0,4><<<dim3(kC / 128, kRows / 128, 8), 256, 0, stream>>>(
            ff_hf, pWT, pB, x, nullptr, nullptr, kRows, kC, kFF);
    }
    tanh_kernel<<<kRows * kC / 1024, 256, 0, stream>>>(x);
}

// Round 14
// 671.579 us; speedup vs baseline: 1.2969x; 1.2969x over previous
//
#include <hip/hip_runtime.h>
#include <hip/hip_bf16.h>
#include <math.h>

// Problem constants
constexpr int kB   = 2;
constexpr int kL   = 1024;
constexpr int kOBS = 64;
constexpr int kACT = 16;
constexpr int kC   = 1024;
constexpr int kH   = 16;
constexpr int kDH  = 64;
constexpr int kFF  = 4096;
constexpr int kNL  = 4;
constexpr int kRows = kB * kL;          // 2048
constexpr int kOE = 512, kAE = 256, kRE = 128, kTE = 128;

typedef _Float16 f16x8 __attribute__((ext_vector_type(8)));
typedef _Float16 f16x4 __attribute__((ext_vector_type(4)));
typedef float    f32x4 __attribute__((ext_vector_type(4)));

__device__ __forceinline__ unsigned short f2h(float x) {
    return __builtin_bit_cast(unsigned short, (_Float16)x);
}
__device__ __forceinline__ void gload_lds16(const void* g, void* l) {
    __builtin_amdgcn_global_load_lds(
        (const __attribute__((address_space(1))) unsigned int*)g,
        (__attribute__((address_space(3))) unsigned int*)l, 16, 0, 0);
}

// ---------------------------------------------------------------------------
// 1. Transition batchnorm stats
// ---------------------------------------------------------------------------
__global__ __launch_bounds__(256) void tran_stats_kernel(
    const float* __restrict__ obs, float* __restrict__ tm, float* __restrict__ tv)
{
    const int f = blockIdx.x;
    const int tid = threadIdx.x;
    float sum = 0.f, sq = 0.f;
    for (int r = tid; r < kRows; r += 256) {
        const int t = r & (kL - 1);
        float d = 0.f;
        if (t > 0) {
            const float cur  = obs[(size_t)r * kOBS + f];
            const float prev = obs[(size_t)(r - 1) * kOBS + f];
            d = cur - prev;
        }
        sum += d; sq += d * d;
    }
    for (int off = 32; off > 0; off >>= 1) {
        sum += __shfl_down(sum, off);
        sq  += __shfl_down(sq, off);
    }
    __shared__ float sa[4], sb[4];
    if ((tid & 63) == 0) { sa[tid >> 6] = sum; sb[tid >> 6] = sq; }
    __syncthreads();
    if (tid == 0) {
        const float ts = sa[0] + sa[1] + sa[2] + sa[3];
        const float tq = sb[0] + sb[1] + sb[2] + sb[3];
        const float m = ts / (float)kRows;
        tm[f] = m;
        tv[f] = tq / (float)kRows - m * m;
    }
}

// ---------------------------------------------------------------------------
// 2. Encoder (writes fp32 residual stream)
// ---------------------------------------------------------------------------
__global__ __launch_bounds__(256) void encode_kernel(
    const float* __restrict__ obs, const float* __restrict__ act, const float* __restrict__ rew,
    const float* __restrict__ obs_W, const float* __restrict__ obs_b,
    const float* __restrict__ act_W, const float* __restrict__ act_b,
    const float* __restrict__ rew_W, const float* __restrict__ rew_b,
    const float* __restrict__ tr_W,  const float* __restrict__ tr_b,
    const float* __restrict__ bn_g,  const float* __restrict__ bn_b,
    const float* __restrict__ tm,    const float* __restrict__ tv,
    float* __restrict__ enc)
{
    const int row = blockIdx.x;
    const int t = row & (kL - 1);
    const int tid = threadIdx.x;
    __shared__ float s_obs2[kOBS];
    __shared__ float s_tran[kOBS];
    __shared__ float s_act[kACT];
    __shared__ float s_rew;
    if (tid < kOBS) {
        const float cur  = obs[(size_t)row * kOBS + tid];
        const float prev = (t > 0) ? obs[(size_t)(row - 1) * kOBS + tid] : cur;
        s_obs2[tid] = prev;
        const float tr = cur - prev;
        s_tran[tid] = (tr - tm[tid]) * rsqrtf(tv[tid] + 1e-5f) * bn_g[tid] + bn_b[tid];
    } else if (tid < kOBS + kACT) {
        s_act[tid - kOBS] = act[(size_t)row * kACT + (tid - kOBS)];
    } else if (tid == kOBS + kACT) {
        s_rew = rew[row];
    }
    __syncthreads();
    float* er = enc + (size_t)row * kC;
    #pragma unroll
    for (int s = 0; s < 4; ++s) {
        const int c = tid + s * 256;
        float v;
        if (c < kOE) {
            v = obs_b[c];
            #pragma unroll
            for (int k = 0; k < kOBS; ++k) v += s_obs2[k] * obs_W[k * kOE + c];
        } else if (c < kOE + kAE) {
            const int cc = c - kOE;
            v = act_b[cc];
            #pragma unroll
            for (int k = 0; k < kACT; ++k) v += s_act[k] * act_W[k * kAE + cc];
        } else if (c < kOE + kAE + kRE) {
            const int cc = c - (kOE + kAE);
            v = s_rew * rew_W[cc] + rew_b[cc];
        } else {
            const int cc = c - (kOE + kAE + kRE);
            v = tr_b[cc];
            #pragma unroll
            for (int k = 0; k < kOBS; ++k) v += s_tran[k] * tr_W[k * kTE + cc];
        }
        er[c] = v;
    }
}

// ---------------------------------------------------------------------------
// 3. LayerNorm: fp32 in -> fp16 out
// ---------------------------------------------------------------------------
__global__ __launch_bounds__(256) void ln_kernel(
    const float* __restrict__ x, const float* __restrict__ w,
    const float* __restrict__ b, unsigned short* __restrict__ out)
{
    const int row = blockIdx.x;
    const int tid = threadIdx.x;
    const float4 xv = *reinterpret_cast<const float4*>(&x[(size_t)row * kC + tid * 4]);
    float s = xv.x + xv.y + xv.z + xv.w;
    float q = xv.x * xv.x + xv.y * xv.y + xv.z * xv.z + xv.w * xv.w;
    for (int off = 32; off > 0; off >>= 1) {
        s += __shfl_down(s, off);
        q += __shfl_down(q, off);
    }
    __shared__ float sa[4], sb[4];
    if ((tid & 63) == 0) { sa[tid >> 6] = s; sb[tid >> 6] = q; }
    __syncthreads();
    const float ts = sa[0] + sa[1] + sa[2] + sa[3];
    const float tq = sb[0] + sb[1] + sb[2] + sb[3];
    const float mean = ts * (1.f / kC);
    const float var  = tq * (1.f / kC) - mean * mean;
    const float rstd = rsqrtf(var + 1e-5f);
    const float4 wv = *reinterpret_cast<const float4*>(&w[tid * 4]);
    const float4 bv = *reinterpret_cast<const float4*>(&b[tid * 4]);
    ushort4 o;
    o.x = f2h((xv.x - mean) * rstd * wv.x + bv.x);
    o.y = f2h((xv.y - mean) * rstd * wv.y + bv.y);
    o.z = f2h((xv.z - mean) * rstd * wv.z + bv.z);
    o.w = f2h((xv.w - mean) * rstd * wv.w + bv.w);
    *reinterpret_cast<ushort4*>(&out[(size_t)row * kC + tid * 4]) = o;
}

// ---------------------------------------------------------------------------
// 4a. Per-layer weight convert+transpose, single launch (3072 tiles).
// ---------------------------------------------------------------------------
__device__ __forceinline__ void convT_tile(
    const float* __restrict__ W, unsigned short* __restrict__ WT,
    int K, int N, int k0, int n0, int tid)
{
    __shared__ unsigned short t[64][68];
    const int r = tid >> 4, c4 = (tid & 15) * 4;
    #pragma unroll
    for (int s = 0; s < 4; ++s) {
        const int rr = r + s * 16;
        const float4 v = *reinterpret_cast<const float4*>(&W[(size_t)(k0 + rr) * N + n0 + c4]);
        t[rr][c4 + 0] = f2h(v.x);
        t[rr][c4 + 1] = f2h(v.y);
        t[rr][c4 + 2] = f2h(v.z);
        t[rr][c4 + 3] = f2h(v.w);
    }
    __syncthreads();
    #pragma unroll
    for (int s = 0; s < 4; ++s) {
        const int rn = r + s * 16;
        ushort4 o;
        o.x = t[c4 + 0][rn];
        o.y = t[c4 + 1][rn];
        o.z = t[c4 + 2][rn];
        o.w = t[c4 + 3][rn];
        *reinterpret_cast<ushort4*>(&WT[(size_t)(n0 + rn) * K + k0 + c4]) = o;
    }
}

__global__ __launch_bounds__(256) void convert_layer_kernel(
    const float* __restrict__ qW, const float* __restrict__ oW,
    const float* __restrict__ fW, const float* __restrict__ pW,
    unsigned short* __restrict__ qWT, unsigned short* __restrict__ oWT,
    unsigned short* __restrict__ fWT, unsigned short* __restrict__ pWT)
{
    int bid = blockIdx.x;                    // 3072 tiles total
    const int tid = threadIdx.x;
    if (bid < 768)  {                        // qW: K=1024, N=3072 (48 n-tiles)
        convT_tile(qW, qWT, 1024, 3072, (bid / 48) * 64, (bid % 48) * 64, tid);
    } else if (bid < 1024) {                 // oW: 1024x1024 (16)
        bid -= 768;
        convT_tile(oW, oWT, 1024, 1024, (bid / 16) * 64, (bid % 16) * 64, tid);
    } else if (bid < 2048) {                 // fW: K=1024, N=4096 (64)
        bid -= 1024;
        convT_tile(fW, fWT, 1024, 4096, (bid / 64) * 64, (bid % 64) * 64, tid);
    } else {                                 // pW: K=4096, N=1024 (16)
        bid -= 2048;
        convT_tile(pW, pWT, 4096, 1024, (bid / 16) * 64, (bid % 16) * 64, tid);
    }
}

// ---------------------------------------------------------------------------
// 4b. fp16 MFMA GEMM (round-10 best config): BK=64, double-buffered,
//     read-then-stage order, 8-slot XOR swizzle, XCD-aware block swizzle.
//     MODE 0: f32 out (+RES/RELU). MODE 1: f16 out. MODE 2: qkv special.
//     MODE 4: split-K atomicAdd into Cf.
// ---------------------------------------------------------------------------
template<int RELU, int RES, int MODE>
__global__ __launch_bounds__(256) void gemm_f16_kernel(
    const unsigned short* __restrict__ A,   // [M][K] fp16
    const unsigned short* __restrict__ BT,  // [N][K] fp16
    const float* __restrict__ bias,
    float* __restrict__ Cf, unsigned short* __restrict__ Ch,
    unsigned short* __restrict__ Cv,
    int M, int N, int K)
{
    __shared__ __align__(16) unsigned short As[2][128 * 64];   // 32 KB
    __shared__ __align__(16) unsigned short Bs[2][128 * 64];   // 32 KB
    const int tid = threadIdx.x;
    const int lane = tid & 63;
    const int wv   = tid >> 6;
    const int wr = wv >> 1, wc = wv & 1;

    // XCD-aware swizzle (bijective: all our grids are divisible by 8)
    const int nx  = gridDim.x;
    const int nxy = gridDim.x * gridDim.y;
    int flat = blockIdx.x + nx * blockIdx.y + nxy * blockIdx.z;
    const int cpx = (nxy * gridDim.z) >> 3;
    flat = (flat & 7) * cpx + (flat >> 3);
    const int bx = flat % nx;
    const int by = (flat / nx) % gridDim.y;
    const int bz = flat / nxy;

    const int bm = by * 128;
    const int bn = bx * 128;
    const int ksz  = K / gridDim.z;
    const int kbeg = bz * ksz;
    const int kend = kbeg + ksz;

    // staging: row stride 64 halves = 128 B = 8 slots of 16 B.
    const int grow = tid >> 3;                  // 0..31
    const int gs   = (tid & 7) ^ (grow & 7);    // pre-swizzled global slot

    const int fr = lane & 15;
    const int kb = lane >> 4;                   // 0..3

    auto stage = [&](int k0, int buf) {
        #pragma unroll
        for (int c = 0; c < 4; ++c) {
            gload_lds16(A  + (size_t)(bm + c * 32 + grow) * K + k0 + gs * 8,
                        (char*)&As[buf][0] + c * 4096 + wv * 1024);
            gload_lds16(BT + (size_t)(bn + c * 32 + grow) * K + k0 + gs * 8,
                        (char*)&Bs[buf][0] + c * 4096 + wv * 1024);
        }
    };

    f32x4 acc[4][4] = {};

    stage(kbeg, 0);
    __syncthreads();                 // prologue loads resident (vmcnt -> 0)
    int cur = 0;
    for (int k0 = kbeg; k0 < kend; k0 += 64) {
        // 1) ds_read all fragments of buf[cur]
        f16x8 a[2][4], b[2][4];
        #pragma unroll
        for (int kf = 0; kf < 2; ++kf) {
            #pragma unroll
            for (int m = 0; m < 4; ++m) {
                const int row = wr * 64 + m * 16 + fr;
                a[kf][m] = *reinterpret_cast<const f16x8*>(
                    &As[cur][row * 64 + (((kf * 4 + kb) ^ (row & 7)) * 8)]);
            }
            #pragma unroll
            for (int n = 0; n < 4; ++n) {
                const int row = wc * 64 + n * 16 + fr;
                b[kf][n] = *reinterpret_cast<const f16x8*>(
                    &Bs[cur][row * 64 + (((kf * 4 + kb) ^ (row & 7)) * 8)]);
            }
        }
        // 2) issue next-tile stage; latency hides under the MFMAs
        if (k0 + 64 < kend) stage(k0 + 64, cur ^ 1);
        // 3) MFMA
        #pragma unroll
        for (int kf = 0; kf < 2; ++kf)
            #pragma unroll
            for (int m = 0; m < 4; ++m)
                #pragma unroll
                for (int n = 0; n < 4; ++n)
                    acc[m][n] = __builtin_amdgcn_mfma_f32_16x16x32_f16(
                        a[kf][m], b[kf][n], acc[m][n], 0, 0, 0);

        __syncthreads();             // drains stage; next buf ready
        cur ^= 1;
    }

    const int fq = lane >> 4;
    if (MODE == 4) {                 // split-K atomic accumulate (RES via x)
        const bool addb = (bz == 0);
        #pragma unroll
        for (int n = 0; n < 4; ++n) {
            const int c = bn + wc * 64 + n * 16 + fr;
            const float bv = addb ? bias[c] : 0.f;
            #pragma unroll
            for (int m = 0; m < 4; ++m) {
                #pragma unroll
                for (int j = 0; j < 4; ++j) {
                    const int r = bm + wr * 64 + m * 16 + fq * 4 + j;
                    atomicAdd(&Cf[(size_t)r * N + c], acc[m][n][j] + bv);
                }
            }
        }
        return;
    }
    if (MODE == 2) {
        if (bn < 2 * kC) {          // Q,K region -> qk f16 [row][2048]
            #pragma unroll
            for (int n = 0; n < 4; ++n) {
                const int c = bn + wc * 64 + n * 16 + fr;
                const float bv = bias[c];
                #pragma unroll
                for (int m = 0; m < 4; ++m) {
                    #pragma unroll
                    for (int j = 0; j < 4; ++j) {
                        const int r = bm + wr * 64 + m * 16 + fq * 4 + j;
                        Ch[(size_t)r * (2 * kC) + c] = f2h(acc[m][n][j] + bv);
                    }
                }
            }
        } else {                    // V region -> vt[b][h][d][t] f16
            #pragma unroll
            for (int n = 0; n < 4; ++n) {
                const int c  = bn + wc * 64 + n * 16 + fr;
                const int cc = c - 2 * kC;
                const int hh = cc >> 6, dd = cc & 63;
                const float bv = bias[c];
                #pragma unroll
                for (int m = 0; m < 4; ++m) {
                    const int rr = bm + wr * 64 + m * 16 + fq * 4;
                    const int bb = rr >> 10, t0 = rr & 1023;
                    f16x4 pk;
                    #pragma unroll
                    for (int j = 0; j < 4; ++j) pk[j] = (_Float16)(acc[m][n][j] + bv);
                    *reinterpret_cast<f16x4*>(
                        &Cv[((size_t)(bb * kH + hh) * kDH + dd) * kL + t0]) = pk;
                }
            }
        }
        return;
    }
    #pragma unroll
    for (int n = 0; n < 4; ++n) {
        const int c = bn + wc * 64 + n * 16 + fr;
        const float bv = bias[c];
        #pragma unroll
        for (int m = 0; m < 4; ++m) {
            #pragma unroll
            for (int j = 0; j < 4; ++j) {
                const int r = bm + wr * 64 + m * 16 + fq * 4 + j;
                float v = acc[m][n][j] + bv;
                if (RES)  v += Cf[(size_t)r * N + c];
                if (RELU) v = fmaxf(v, 0.f);
                if (MODE == 1) Ch[(size_t)r * N + c] = f2h(v);
                else           Cf[(size_t)r * N + c] = v;
            }
        }
    }
}

// ---------------------------------------------------------------------------
// 5. MFMA flash attention, LDS-staged K/V^T with T14 async-STAGE split:
//    global->REG prefetch issued right after the LDS writes of the current
//    tile; loads stay in flight across the RAW s_barrier (no vmcnt drain)
//    and complete during the compute phase. Q fragments direct per-lane.
//    Barriers: raw s_barrier + manual lgkmcnt(0) + sched_barrier(0) (rule 18).
// ---------------------------------------------------------------------------
__device__ __forceinline__ int swz(int row, int slot) {
    return row * 64 + ((slot ^ (row & 7)) * 8);   // ushort index, 16B-aligned
}

__global__ __launch_bounds__(256) void attn_mfma_kernel(
    const unsigned short* __restrict__ qk,   // [2048][2048] f16 (Q | K)
    const unsigned short* __restrict__ vt,   // [2][16][64][1024] f16  V^T
    unsigned short* __restrict__ o)          // [2048][1024] f16
{
    const int bid = blockIdx.x;            // 512 blocks
    const int bh  = bid & 31;
    const int qb  = ((bid >> 5) + bh) & 15;   // shear: balance causal work
    const int b   = bh >> 4;
    const int h   = bh & 15;
    const int tid  = threadIdx.x;
    const int lane = tid & 63;
    const int wv   = tid >> 6;
    const int fr = lane & 15;              // q index within wave
    const int g  = lane >> 4;              // k-group

    __shared__ __align__(16) unsigned short Ks[64 * 64];    // 8 KB
    __shared__ __align__(16) unsigned short Vts[64 * 64];   // 8 KB
    __shared__ __align__(16) unsigned short Ps[64 * 64];    // 8 KB

    const int qlo = qb * 64;
    const int qg_row = qlo + wv * 16 + fr;

    // Q fragments direct from global (per-lane 2x16B, once), prescaled by 1/8
    f16x8 qfrag[2];
    {
        const unsigned short* qg = &qk[(size_t)(b * kL + qg_row) * (2 * kC) + h * kDH];
        #pragma unroll
        for (int kf = 0; kf < 2; ++kf) {
            f16x8 v = *reinterpret_cast<const f16x8*>(&qg[(kf * 4 + g) * 8]);
            #pragma unroll
            for (int i = 0; i < 8; ++i) v[i] *= (_Float16)0.125f;
            qfrag[kf] = v;
        }
    }

    // staging geometry: row sr = tid>>2, slots ss and ss+4
    const int sr = tid >> 2;
    const int ss = tid & 3;
    const unsigned short* kbase = &qk[(size_t)(b * kL) * (2 * kC) + kC + h * kDH];
    const unsigned short* vbase = &vt[(size_t)(b * kH + h) * kDH * kL];

    // prologue: prefetch tile 0 into registers
    f16x8 kc0 = *reinterpret_cast<const f16x8*>(&kbase[(size_t)sr * (2 * kC) + ss * 8]);
    f16x8 kc1 = *reinterpret_cast<const f16x8*>(&kbase[(size_t)sr * (2 * kC) + (ss + 4) * 8]);
    f16x8 vc0 = *reinterpret_cast<const f16x8*>(&vbase[(size_t)sr * kL + ss * 8]);
    f16x8 vc1 = *reinterpret_cast<const f16x8*>(&vbase[(size_t)sr * kL + (ss + 4) * 8]);

    float m = -INFINITY, l = 0.f;
    f32x4 acc_o[4] = {};

    for (int k0 = 0; k0 <= qlo; k0 += 64) {
        // all waves finished reading the previous tile's Ks/Vts
        asm volatile("s_waitcnt lgkmcnt(0)" ::: "memory");
        __builtin_amdgcn_sched_barrier(0);
        __builtin_amdgcn_s_barrier();
        __builtin_amdgcn_sched_barrier(0);

        // write current-tile regs -> LDS (compiler waits vmcnt for the regs)
        *reinterpret_cast<f16x8*>(&Ks[swz(sr, ss)])      = kc0;
        *reinterpret_cast<f16x8*>(&Ks[swz(sr, ss + 4)])  = kc1;
        *reinterpret_cast<f16x8*>(&Vts[swz(sr, ss)])     = vc0;
        *reinterpret_cast<f16x8*>(&Vts[swz(sr, ss + 4)]) = vc1;

        // T14: issue next-tile prefetch NOW; stays in flight across the raw
        // barrier and completes under the compute below.
        if (k0 + 64 <= qlo) {
            kc0 = *reinterpret_cast<const f16x8*>(&kbase[(size_t)(k0 + 64 + sr) * (2 * kC) + ss * 8]);
            kc1 = *reinterpret_cast<const f16x8*>(&kbase[(size_t)(k0 + 64 + sr) * (2 * kC) + (ss + 4) * 8]);
            vc0 = *reinterpret_cast<const f16x8*>(&vbase[(size_t)sr * kL + k0 + 64 + ss * 8]);
            vc1 = *reinterpret_cast<const f16x8*>(&vbase[(size_t)sr * kL + k0 + 64 + (ss + 4) * 8]);
        }

        // my LDS writes landed; barrier makes them visible to all waves
        asm volatile("s_waitcnt lgkmcnt(0)" ::: "memory");
        __builtin_amdgcn_sched_barrier(0);
        __builtin_amdgcn_s_barrier();
        __builtin_amdgcn_sched_barrier(0);

        // QK^T (swapped): acc_s[n] = D[key][q]
        f32x4 acc_s[4] = {};
        #pragma unroll
        for (int kf = 0; kf < 2; ++kf) {
            #pragma unroll
            for (int n = 0; n < 4; ++n) {
                const f16x8 kfr = *reinterpret_cast<const f16x8*>(&Ks[swz(n * 16 + fr, kf * 4 + g)]);
                acc_s[n] = __builtin_amdgcn_mfma_f32_16x16x32_f16(kfr, qfrag[kf], acc_s[n], 0, 0, 0);
            }
        }

        if (k0 == qlo) {
            #pragma unroll
            for (int n = 0; n < 4; ++n)
                #pragma unroll
                for (int j = 0; j < 4; ++j)
                    if (k0 + n * 16 + g * 4 + j > qg_row) acc_s[n][j] = -INFINITY;
        }

        float mx = -INFINITY;
        #pragma unroll
        for (int n = 0; n < 4; ++n)
            #pragma unroll
            for (int j = 0; j < 4; ++j) mx = fmaxf(mx, acc_s[n][j]);
        mx = fmaxf(mx, __shfl_xor(mx, 16));
        mx = fmaxf(mx, __shfl_xor(mx, 32));
        const float mn  = fmaxf(m, mx);
        const float fac = __expf(m - mn);
        float p[4][4];
        float psum = 0.f;
        #pragma unroll
        for (int n = 0; n < 4; ++n)
            #pragma unroll
            for (int j = 0; j < 4; ++j) { p[n][j] = __expf(acc_s[n][j] - mn); psum += p[n][j]; }
        psum += __shfl_xor(psum, 16);
        psum += __shfl_xor(psum, 32);
        l = l * fac + psum;
        m = mn;
        #pragma unroll
        for (int dt = 0; dt < 4; ++dt)
            #pragma unroll
            for (int j = 0; j < 4; ++j) acc_o[dt][j] *= fac;

        // P -> LDS f16 (wave-private rows; same-wave in-order DS)
        #pragma unroll
        for (int n = 0; n < 4; ++n) {
            f16x4 pk;
            #pragma unroll
            for (int j = 0; j < 4; ++j) pk[j] = (_Float16)p[n][j];
            *reinterpret_cast<f16x4*>(&Ps[swz(wv * 16 + fr, 2 * n + (g >> 1)) + (g & 1) * 4]) = pk;
        }

        // PV
        #pragma unroll
        for (int kf = 0; kf < 2; ++kf) {
            const f16x8 pf = *reinterpret_cast<const f16x8*>(&Ps[swz(wv * 16 + fr, kf * 4 + g)]);
            #pragma unroll
            for (int dt = 0; dt < 4; ++dt) {
                const f16x8 vf = *reinterpret_cast<const f16x8*>(&Vts[swz(dt * 16 + fr, kf * 4 + g)]);
                acc_o[dt] = __builtin_amdgcn_mfma_f32_16x16x32_f16(vf, pf, acc_o[dt], 0, 0, 0);
            }
        }
    }

    const float rl = 1.f / l;
    unsigned short* ob = &o[(size_t)(b * kL + qg_row) * kC + h * kDH];
    #pragma unroll
    for (int dt = 0; dt < 4; ++dt) {
        f16x4 pk;
        #pragma unroll
        for (int j = 0; j < 4; ++j) pk[j] = (_Float16)(acc_o[dt][j] * rl);
        *reinterpret_cast<f16x4*>(&ob[dt * 16 + g * 4]) = pk;
    }
}

// ---------------------------------------------------------------------------
// 6. Final tanh (in place on d_out)
// ---------------------------------------------------------------------------
__global__ __launch_bounds__(256) void tanh_kernel(float* __restrict__ x)
{
    const size_t i = ((size_t)blockIdx.x * 256 + threadIdx.x) * 4;
    float4 v = *reinterpret_cast<float4*>(&x[i]);
    v.x = tanhf(v.x); v.y = tanhf(v.y); v.z = tanhf(v.z); v.w = tanhf(v.w);
    *reinterpret_cast<float4*>(&x[i]) = v;
}

// ---------------------------------------------------------------------------
extern "C" void kernel_launch(void* const* d_in, const int* in_sizes, int n_in,
                              void* d_out, int out_size, void* d_ws, size_t ws_size,
                              hipStream_t stream)
{
    (void)in_sizes; (void)n_in; (void)out_size; (void)ws_size;
    const float* obs    = (const float*)d_in[0];
    const float* act    = (const float*)d_in[1];
    const float* rew    = (const float*)d_in[2];
    const float* obs_W  = (const float*)d_in[3];
    const float* obs_b  = (const float*)d_in[4];
    const float* act_W  = (const float*)d_in[5];
    const float* act_b  = (const float*)d_in[6];
    const float* rew_W  = (const float*)d_in[7];
    const float* rew_b  = (const float*)d_in[8];
    const float* tr_W   = (const float*)d_in[9];
    const float* tr_b   = (const float*)d_in[10];
    const float* bn_g   = (const float*)d_in[11];
    const float* bn_b   = (const float*)d_in[12];
    const float* ln1_w  = (const float*)d_in[13];
    const float* ln1_b  = (const float*)d_in[14];
    const float* qkv_W  = (const float*)d_in[15];
    const float* qkv_b  = (const float*)d_in[16];
    const float* out_W  = (const float*)d_in[17];
    const float* out_b  = (const float*)d_in[18];
    const float* ln2_w  = (const float*)d_in[19];
    const float* ln2_b  = (const float*)d_in[20];
    const float* fc_W   = (const float*)d_in[21];
    const float* fc_b   = (const float*)d_in[22];
    const float* pj_W   = (const float*)d_in[23];
    const float* pj_b   = (const float*)d_in[24];

    float* x  = (float*)d_out;                     // fp32 residual stream
    float* ws = (float*)d_ws;
    float* tm   = ws;                              // 64
    float* tv   = ws + 64;                         // 64
    unsigned short* wbuf  = (unsigned short*)(ws + 128);  // 12.58M f16 weights
    unsigned short* h_hf  = wbuf + 12582912;       // 2048*1024
    unsigned short* ao_hf = h_hf + (size_t)kRows * kC;    // 2048*1024
    unsigned short* ff_hf = ao_hf + (size_t)kRows * kC;   // 2048*4096
    unsigned short* qk_hf = ff_hf + (size_t)kRows * kFF;  // 2048*2048
    unsigned short* vt_hf = qk_hf + (size_t)kRows * 2 * kC; // 2*16*64*1024
    unsigned short* qWT = wbuf;                    // [3072][1024]
    unsigned short* oWT = qWT + 3 * kC * kC;       // [1024][1024]
    unsigned short* fWT = oWT + kC * kC;           // [4096][1024]
    unsigned short* pWT = fWT + kC * kFF;          // [1024][4096]

    tran_stats_kernel<<<kOBS, 256, 0, stream>>>(obs, tm, tv);
    encode_kernel<<<kRows, 256, 0, stream>>>(obs, act, rew,
        obs_W, obs_b, act_W, act_b, rew_W, rew_b, tr_W, tr_b, bn_g, bn_b, tm, tv, x);

    for (int lyr = 0; lyr < kNL; ++lyr) {
        const float* qW = qkv_W + (size_t)lyr * kC * 3 * kC;
        const float* qB = qkv_b + (size_t)lyr * 3 * kC;
        const float* oW = out_W + (size_t)lyr * kC * kC;
        const float* oB = out_b + (size_t)lyr * kC;
        const float* fW = fc_W + (size_t)lyr * kC * kFF;
        const float* fB = fc_b + (size_t)lyr * kFF;
        const float* pW = pj_W + (size_t)lyr * kFF * kC;
        const float* pB = pj_b + (size_t)lyr * kC;

        convert_layer_kernel<<<3072, 256, 0, stream>>>(
            qW, oW, fW, pW, qWT, oWT, fWT, pWT);

        ln_kernel<<<kRows, 256, 0, stream>>>(x, ln1_w + lyr * kC, ln1_b + lyr * kC, h_hf);
        gemm_f16_kernel<0,0,2><<<dim3(3 * kC / 128, kRows / 128), 256, 0, stream>>>(
            h_hf, qWT, qB, nullptr, qk_hf, vt_hf, kRows, 3 * kC, kC);
        attn_mfma_kernel<<<dim3(512), 256, 0, stream>>>(qk_hf, vt_hf, ao_hf);
        // out projection: split-K=4, atomic accumulate into residual stream
        gemm_f16_kernel<0,0,4><<<dim3(kC / 128, kRows / 128, 4), 256, 0, stream>>>(
            ao_hf, oWT, oB, x, nullptr, nullptr, kRows, kC, kC);
        ln_kernel<<<kRows, 256, 0, stream>>>(x, ln2_w + lyr * kC, ln2_b + lyr * kC, h_hf);
        gemm_f16_kernel<1,0,1><<<dim3(kFF / 128, kRows / 128), 256, 0, stream>>>(
            h_hf, fWT, fB, nullptr, ff_hf, nullptr, kRows, kFF, kC);
        // pj projection: split-K=4, atomic accumulate into residual stream
        gemm_f16_kernel<0,0,4><<<dim3(kC / 128, kRows / 128, 4), 256, 0, stream>>>(
            ff_hf, pWT, pB, x, nullptr, nullptr, kRows, kC, kFF);
    }
    tanh_kernel<<<kRows * kC / 1024, 256, 0, stream>>>(x);
}

// Round 15
// 553.822 us; speedup vs baseline: 1.5726x; 1.2126x over previous
//
#include <hip/hip_runtime.h>
#include <hip/hip_bf16.h>
#include <math.h>

// Problem constants
constexpr int kB   = 2;
constexpr int kL   = 1024;
constexpr int kOBS = 64;
constexpr int kACT = 16;
constexpr int kC   = 1024;
constexpr int kH   = 16;
constexpr int kDH  = 64;
constexpr int kFF  = 4096;
constexpr int kNL  = 4;
constexpr int kRows = kB * kL;          // 2048
constexpr int kOE = 512, kAE = 256, kRE = 128, kTE = 128;

typedef _Float16 f16x8 __attribute__((ext_vector_type(8)));
typedef _Float16 f16x4 __attribute__((ext_vector_type(4)));
typedef float    f32x4 __attribute__((ext_vector_type(4)));

__device__ __forceinline__ unsigned short f2h(float x) {
    return __builtin_bit_cast(unsigned short, (_Float16)x);
}
__device__ __forceinline__ float h2f(unsigned short x) {
    return (float)__builtin_bit_cast(_Float16, x);
}
__device__ __forceinline__ void gload_lds16(const void* g, void* l) {
    __builtin_amdgcn_global_load_lds(
        (const __attribute__((address_space(1))) unsigned int*)g,
        (__attribute__((address_space(3))) unsigned int*)l, 16, 0, 0);
}

// ---------------------------------------------------------------------------
// 1. Transition batchnorm stats
// ---------------------------------------------------------------------------
__global__ __launch_bounds__(256) void tran_stats_kernel(
    const float* __restrict__ obs, float* __restrict__ tm, float* __restrict__ tv)
{
    const int f = blockIdx.x;
    const int tid = threadIdx.x;
    float sum = 0.f, sq = 0.f;
    for (int r = tid; r < kRows; r += 256) {
        const int t = r & (kL - 1);
        float d = 0.f;
        if (t > 0) {
            const float cur  = obs[(size_t)r * kOBS + f];
            const float prev = obs[(size_t)(r - 1) * kOBS + f];
            d = cur - prev;
        }
        sum += d; sq += d * d;
    }
    for (int off = 32; off > 0; off >>= 1) {
        sum += __shfl_down(sum, off);
        sq  += __shfl_down(sq, off);
    }
    __shared__ float sa[4], sb[4];
    if ((tid & 63) == 0) { sa[tid >> 6] = sum; sb[tid >> 6] = sq; }
    __syncthreads();
    if (tid == 0) {
        const float ts = sa[0] + sa[1] + sa[2] + sa[3];
        const float tq = sb[0] + sb[1] + sb[2] + sb[3];
        const float m = ts / (float)kRows;
        tm[f] = m;
        tv[f] = tq / (float)kRows - m * m;
    }
}

// ---------------------------------------------------------------------------
// 2. Encoder (writes fp32 residual stream)
// ---------------------------------------------------------------------------
__global__ __launch_bounds__(256) void encode_kernel(
    const float* __restrict__ obs, const float* __restrict__ act, const float* __restrict__ rew,
    const float* __restrict__ obs_W, const float* __restrict__ obs_b,
    const float* __restrict__ act_W, const float* __restrict__ act_b,
    const float* __restrict__ rew_W, const float* __restrict__ rew_b,
    const float* __restrict__ tr_W,  const float* __restrict__ tr_b,
    const float* __restrict__ bn_g,  const float* __restrict__ bn_b,
    const float* __restrict__ tm,    const float* __restrict__ tv,
    float* __restrict__ enc)
{
    const int row = blockIdx.x;
    const int t = row & (kL - 1);
    const int tid = threadIdx.x;
    __shared__ float s_obs2[kOBS];
    __shared__ float s_tran[kOBS];
    __shared__ float s_act[kACT];
    __shared__ float s_rew;
    if (tid < kOBS) {
        const float cur  = obs[(size_t)row * kOBS + tid];
        const float prev = (t > 0) ? obs[(size_t)(row - 1) * kOBS + tid] : cur;
        s_obs2[tid] = prev;
        const float tr = cur - prev;
        s_tran[tid] = (tr - tm[tid]) * rsqrtf(tv[tid] + 1e-5f) * bn_g[tid] + bn_b[tid];
    } else if (tid < kOBS + kACT) {
        s_act[tid - kOBS] = act[(size_t)row * kACT + (tid - kOBS)];
    } else if (tid == kOBS + kACT) {
        s_rew = rew[row];
    }
    __syncthreads();
    float* er = enc + (size_t)row * kC;
    #pragma unroll
    for (int s = 0; s < 4; ++s) {
        const int c = tid + s * 256;
        float v;
        if (c < kOE) {
            v = obs_b[c];
            #pragma unroll
            for (int k = 0; k < kOBS; ++k) v += s_obs2[k] * obs_W[k * kOE + c];
        } else if (c < kOE + kAE) {
            const int cc = c - kOE;
            v = act_b[cc];
            #pragma unroll
            for (int k = 0; k < kACT; ++k) v += s_act[k] * act_W[k * kAE + cc];
        } else if (c < kOE + kAE + kRE) {
            const int cc = c - (kOE + kAE);
            v = s_rew * rew_W[cc] + rew_b[cc];
        } else {
            const int cc = c - (kOE + kAE + kRE);
            v = tr_b[cc];
            #pragma unroll
            for (int k = 0; k < kOBS; ++k) v += s_tran[k] * tr_W[k * kTE + cc];
        }
        er[c] = v;
    }
}

// ---------------------------------------------------------------------------
// 3. LayerNorm: fp32 in -> fp16 out (standalone, layer-0 ln1 only)
// ---------------------------------------------------------------------------
__global__ __launch_bounds__(256) void ln_kernel(
    const float* __restrict__ x, const float* __restrict__ w,
    const float* __restrict__ b, unsigned short* __restrict__ out)
{
    const int row = blockIdx.x;
    const int tid = threadIdx.x;
    const float4 xv = *reinterpret_cast<const float4*>(&x[(size_t)row * kC + tid * 4]);
    float s = xv.x + xv.y + xv.z + xv.w;
    float q = xv.x * xv.x + xv.y * xv.y + xv.z * xv.z + xv.w * xv.w;
    for (int off = 32; off > 0; off >>= 1) {
        s += __shfl_down(s, off);
        q += __shfl_down(q, off);
    }
    __shared__ float sa[4], sb[4];
    if ((tid & 63) == 0) { sa[tid >> 6] = s; sb[tid >> 6] = q; }
    __syncthreads();
    const float ts = sa[0] + sa[1] + sa[2] + sa[3];
    const float tq = sb[0] + sb[1] + sb[2] + sb[3];
    const float mean = ts * (1.f / kC);
    const float var  = tq * (1.f / kC) - mean * mean;
    const float rstd = rsqrtf(var + 1e-5f);
    const float4 wv = *reinterpret_cast<const float4*>(&w[tid * 4]);
    const float4 bv = *reinterpret_cast<const float4*>(&b[tid * 4]);
    ushort4 o;
    o.x = f2h((xv.x - mean) * rstd * wv.x + bv.x);
    o.y = f2h((xv.y - mean) * rstd * wv.y + bv.y);
    o.z = f2h((xv.z - mean) * rstd * wv.z + bv.z);
    o.w = f2h((xv.w - mean) * rstd * wv.w + bv.w);
    *reinterpret_cast<ushort4*>(&out[(size_t)row * kC + tid * 4]) = o;
}

// ---------------------------------------------------------------------------
// 3b. Fused split-K reduce + residual add + LayerNorm:
//     x[row] += sum_z part[z][row]; h[row] = LN(x[row]) in f16.
// ---------------------------------------------------------------------------
__global__ __launch_bounds__(256) void reduce_ln_kernel(
    const unsigned short* __restrict__ part,   // [4][kRows][kC] f16
    const float* __restrict__ w, const float* __restrict__ b,
    float* __restrict__ x, unsigned short* __restrict__ h)
{
    const int row = blockIdx.x;
    const int tid = threadIdx.x;
    const size_t base = (size_t)row * kC + tid * 4;
    float4 xv = *reinterpret_cast<const float4*>(&x[base]);
    #pragma unroll
    for (int z = 0; z < 4; ++z) {
        const ushort4 p = *reinterpret_cast<const ushort4*>(
            &part[(size_t)z * kRows * kC + base]);
        xv.x += h2f(p.x); xv.y += h2f(p.y); xv.z += h2f(p.z); xv.w += h2f(p.w);
    }
    *reinterpret_cast<float4*>(&x[base]) = xv;

    float s = xv.x + xv.y + xv.z + xv.w;
    float q = xv.x * xv.x + xv.y * xv.y + xv.z * xv.z + xv.w * xv.w;
    for (int off = 32; off > 0; off >>= 1) {
        s += __shfl_down(s, off);
        q += __shfl_down(q, off);
    }
    __shared__ float sa[4], sb[4];
    if ((tid & 63) == 0) { sa[tid >> 6] = s; sb[tid >> 6] = q; }
    __syncthreads();
    const float ts = sa[0] + sa[1] + sa[2] + sa[3];
    const float tq = sb[0] + sb[1] + sb[2] + sb[3];
    const float mean = ts * (1.f / kC);
    const float var  = tq * (1.f / kC) - mean * mean;
    const float rstd = rsqrtf(var + 1e-5f);
    const float4 wv = *reinterpret_cast<const float4*>(&w[tid * 4]);
    const float4 bv = *reinterpret_cast<const float4*>(&b[tid * 4]);
    ushort4 o;
    o.x = f2h((xv.x - mean) * rstd * wv.x + bv.x);
    o.y = f2h((xv.y - mean) * rstd * wv.y + bv.y);
    o.z = f2h((xv.z - mean) * rstd * wv.z + bv.z);
    o.w = f2h((xv.w - mean) * rstd * wv.w + bv.w);
    *reinterpret_cast<ushort4*>(&h[base]) = o;
}

// ---------------------------------------------------------------------------
// 3c. Fused split-K reduce + residual add + tanh (final layer epilogue)
// ---------------------------------------------------------------------------
__global__ __launch_bounds__(256) void reduce_tanh_kernel(
    const unsigned short* __restrict__ part, float* __restrict__ x)
{
    const size_t base = ((size_t)blockIdx.x * 256 + threadIdx.x) * 4;
    float4 xv = *reinterpret_cast<const float4*>(&x[base]);
    #pragma unroll
    for (int z = 0; z < 4; ++z) {
        const ushort4 p = *reinterpret_cast<const ushort4*>(
            &part[(size_t)z * kRows * kC + base]);
        xv.x += h2f(p.x); xv.y += h2f(p.y); xv.z += h2f(p.z); xv.w += h2f(p.w);
    }
    xv.x = tanhf(xv.x); xv.y = tanhf(xv.y); xv.z = tanhf(xv.z); xv.w = tanhf(xv.w);
    *reinterpret_cast<float4*>(&x[base]) = xv;
}

// ---------------------------------------------------------------------------
// 4a. Per-layer weight convert+transpose, single launch (3072 tiles).
// ---------------------------------------------------------------------------
__device__ __forceinline__ void convT_tile(
    const float* __restrict__ W, unsigned short* __restrict__ WT,
    int K, int N, int k0, int n0, int tid)
{
    __shared__ unsigned short t[64][68];
    const int r = tid >> 4, c4 = (tid & 15) * 4;
    #pragma unroll
    for (int s = 0; s < 4; ++s) {
        const int rr = r + s * 16;
        const float4 v = *reinterpret_cast<const float4*>(&W[(size_t)(k0 + rr) * N + n0 + c4]);
        t[rr][c4 + 0] = f2h(v.x);
        t[rr][c4 + 1] = f2h(v.y);
        t[rr][c4 + 2] = f2h(v.z);
        t[rr][c4 + 3] = f2h(v.w);
    }
    __syncthreads();
    #pragma unroll
    for (int s = 0; s < 4; ++s) {
        const int rn = r + s * 16;
        ushort4 o;
        o.x = t[c4 + 0][rn];
        o.y = t[c4 + 1][rn];
        o.z = t[c4 + 2][rn];
        o.w = t[c4 + 3][rn];
        *reinterpret_cast<ushort4*>(&WT[(size_t)(n0 + rn) * K + k0 + c4]) = o;
    }
}

__global__ __launch_bounds__(256) void convert_layer_kernel(
    const float* __restrict__ qW, const float* __restrict__ oW,
    const float* __restrict__ fW, const float* __restrict__ pW,
    unsigned short* __restrict__ qWT, unsigned short* __restrict__ oWT,
    unsigned short* __restrict__ fWT, unsigned short* __restrict__ pWT)
{
    int bid = blockIdx.x;                    // 3072 tiles total
    const int tid = threadIdx.x;
    if (bid < 768)  {                        // qW: K=1024, N=3072 (48 n-tiles)
        convT_tile(qW, qWT, 1024, 3072, (bid / 48) * 64, (bid % 48) * 64, tid);
    } else if (bid < 1024) {                 // oW: 1024x1024 (16)
        bid -= 768;
        convT_tile(oW, oWT, 1024, 1024, (bid / 16) * 64, (bid % 16) * 64, tid);
    } else if (bid < 2048) {                 // fW: K=1024, N=4096 (64)
        bid -= 1024;
        convT_tile(fW, fWT, 1024, 4096, (bid / 64) * 64, (bid % 64) * 64, tid);
    } else {                                 // pW: K=4096, N=1024 (16)
        bid -= 2048;
        convT_tile(pW, pWT, 4096, 1024, (bid / 16) * 64, (bid % 16) * 64, tid);
    }
}

// ---------------------------------------------------------------------------
// 4b. fp16 MFMA GEMM (round-10 best config): BK=64, double-buffered,
//     read-then-stage order, 8-slot XOR swizzle, XCD-aware block swizzle.
//     MODE 0: f32 out (+RES/RELU). MODE 1: f16 out. MODE 2: qkv special.
//     MODE 5: split-K f16 partial store to Ch[z][M][N] (bias at z==0).
// ---------------------------------------------------------------------------
template<int RELU, int RES, int MODE>
__global__ __launch_bounds__(256) void gemm_f16_kernel(
    const unsigned short* __restrict__ A,   // [M][K] fp16
    const unsigned short* __restrict__ BT,  // [N][K] fp16
    const float* __restrict__ bias,
    float* __restrict__ Cf, unsigned short* __restrict__ Ch,
    unsigned short* __restrict__ Cv,
    int M, int N, int K)
{
    __shared__ __align__(16) unsigned short As[2][128 * 64];   // 32 KB
    __shared__ __align__(16) unsigned short Bs[2][128 * 64];   // 32 KB
    const int tid = threadIdx.x;
    const int lane = tid & 63;
    const int wv   = tid >> 6;
    const int wr = wv >> 1, wc = wv & 1;

    // XCD-aware swizzle (bijective: all our grids are divisible by 8)
    const int nx  = gridDim.x;
    const int nxy = gridDim.x * gridDim.y;
    int flat = blockIdx.x + nx * blockIdx.y + nxy * blockIdx.z;
    const int cpx = (nxy * gridDim.z) >> 3;
    flat = (flat & 7) * cpx + (flat >> 3);
    const int bx = flat % nx;
    const int by = (flat / nx) % gridDim.y;
    const int bz = flat / nxy;

    const int bm = by * 128;
    const int bn = bx * 128;
    const int ksz  = K / gridDim.z;
    const int kbeg = bz * ksz;
    const int kend = kbeg + ksz;

    // staging: row stride 64 halves = 128 B = 8 slots of 16 B.
    const int grow = tid >> 3;                  // 0..31
    const int gs   = (tid & 7) ^ (grow & 7);    // pre-swizzled global slot

    const int fr = lane & 15;
    const int kb = lane >> 4;                   // 0..3

    auto stage = [&](int k0, int buf) {
        #pragma unroll
        for (int c = 0; c < 4; ++c) {
            gload_lds16(A  + (size_t)(bm + c * 32 + grow) * K + k0 + gs * 8,
                        (char*)&As[buf][0] + c * 4096 + wv * 1024);
            gload_lds16(BT + (size_t)(bn + c * 32 + grow) * K + k0 + gs * 8,
                        (char*)&Bs[buf][0] + c * 4096 + wv * 1024);
        }
    };

    f32x4 acc[4][4] = {};

    stage(kbeg, 0);
    __syncthreads();                 // prologue loads resident (vmcnt -> 0)
    int cur = 0;
    for (int k0 = kbeg; k0 < kend; k0 += 64) {
        // 1) ds_read all fragments of buf[cur]
        f16x8 a[2][4], b[2][4];
        #pragma unroll
        for (int kf = 0; kf < 2; ++kf) {
            #pragma unroll
            for (int m = 0; m < 4; ++m) {
                const int row = wr * 64 + m * 16 + fr;
                a[kf][m] = *reinterpret_cast<const f16x8*>(
                    &As[cur][row * 64 + (((kf * 4 + kb) ^ (row & 7)) * 8)]);
            }
            #pragma unroll
            for (int n = 0; n < 4; ++n) {
                const int row = wc * 64 + n * 16 + fr;
                b[kf][n] = *reinterpret_cast<const f16x8*>(
                    &Bs[cur][row * 64 + (((kf * 4 + kb) ^ (row & 7)) * 8)]);
            }
        }
        // 2) issue next-tile stage; latency hides under the MFMAs
        if (k0 + 64 < kend) stage(k0 + 64, cur ^ 1);
        // 3) MFMA
        #pragma unroll
        for (int kf = 0; kf < 2; ++kf)
            #pragma unroll
            for (int m = 0; m < 4; ++m)
                #pragma unroll
                for (int n = 0; n < 4; ++n)
                    acc[m][n] = __builtin_amdgcn_mfma_f32_16x16x32_f16(
                        a[kf][m], b[kf][n], acc[m][n], 0, 0, 0);

        __syncthreads();             // drains stage; next buf ready
        cur ^= 1;
    }

    const int fq = lane >> 4;
    if (MODE == 5) {                 // split-K f16 partial store (no atomics)
        unsigned short* pp = Ch + (size_t)bz * M * N;
        const bool addb = (bz == 0);
        #pragma unroll
        for (int n = 0; n < 4; ++n) {
            const int c = bn + wc * 64 + n * 16 + fr;
            const float bv = addb ? bias[c] : 0.f;
            #pragma unroll
            for (int m = 0; m < 4; ++m) {
                #pragma unroll
                for (int j = 0; j < 4; ++j) {
                    const int r = bm + wr * 64 + m * 16 + fq * 4 + j;
                    pp[(size_t)r * N + c] = f2h(acc[m][n][j] + bv);
                }
            }
        }
        return;
    }
    if (MODE == 2) {
        if (bn < 2 * kC) {          // Q,K region -> qk f16 [row][2048]
            #pragma unroll
            for (int n = 0; n < 4; ++n) {
                const int c = bn + wc * 64 + n * 16 + fr;
                const float bv = bias[c];
                #pragma unroll
                for (int m = 0; m < 4; ++m) {
                    #pragma unroll
                    for (int j = 0; j < 4; ++j) {
                        const int r = bm + wr * 64 + m * 16 + fq * 4 + j;
                        Ch[(size_t)r * (2 * kC) + c] = f2h(acc[m][n][j] + bv);
                    }
                }
            }
        } else {                    // V region -> vt[b][h][d][t] f16
            #pragma unroll
            for (int n = 0; n < 4; ++n) {
                const int c  = bn + wc * 64 + n * 16 + fr;
                const int cc = c - 2 * kC;
                const int hh = cc >> 6, dd = cc & 63;
                const float bv = bias[c];
                #pragma unroll
                for (int m = 0; m < 4; ++m) {
                    const int rr = bm + wr * 64 + m * 16 + fq * 4;
                    const int bb = rr >> 10, t0 = rr & 1023;
                    f16x4 pk;
                    #pragma unroll
                    for (int j = 0; j < 4; ++j) pk[j] = (_Float16)(acc[m][n][j] + bv);
                    *reinterpret_cast<f16x4*>(
                        &Cv[((size_t)(bb * kH + hh) * kDH + dd) * kL + t0]) = pk;
                }
            }
        }
        return;
    }
    #pragma unroll
    for (int n = 0; n < 4; ++n) {
        const int c = bn + wc * 64 + n * 16 + fr;
        const float bv = bias[c];
        #pragma unroll
        for (int m = 0; m < 4; ++m) {
            #pragma unroll
            for (int j = 0; j < 4; ++j) {
                const int r = bm + wr * 64 + m * 16 + fq * 4 + j;
                float v = acc[m][n][j] + bv;
                if (RES)  v += Cf[(size_t)r * N + c];
                if (RELU) v = fmaxf(v, 0.f);
                if (MODE == 1) Ch[(size_t)r * N + c] = f2h(v);
                else           Cf[(size_t)r * N + c] = v;
            }
        }
    }
}

// ---------------------------------------------------------------------------
// 5. MFMA flash attention (round-14 T14 pipeline, unchanged)
// ---------------------------------------------------------------------------
__device__ __forceinline__ int swz(int row, int slot) {
    return row * 64 + ((slot ^ (row & 7)) * 8);   // ushort index, 16B-aligned
}

__global__ __launch_bounds__(256) void attn_mfma_kernel(
    const unsigned short* __restrict__ qk,   // [2048][2048] f16 (Q | K)
    const unsigned short* __restrict__ vt,   // [2][16][64][1024] f16  V^T
    unsigned short* __restrict__ o)          // [2048][1024] f16
{
    const int bid = blockIdx.x;            // 512 blocks
    const int bh  = bid & 31;
    const int qb  = ((bid >> 5) + bh) & 15;   // shear: balance causal work
    const int b   = bh >> 4;
    const int h   = bh & 15;
    const int tid  = threadIdx.x;
    const int lane = tid & 63;
    const int wv   = tid >> 6;
    const int fr = lane & 15;              // q index within wave
    const int g  = lane >> 4;              // k-group

    __shared__ __align__(16) unsigned short Ks[64 * 64];    // 8 KB
    __shared__ __align__(16) unsigned short Vts[64 * 64];   // 8 KB
    __shared__ __align__(16) unsigned short Ps[64 * 64];    // 8 KB

    const int qlo = qb * 64;
    const int qg_row = qlo + wv * 16 + fr;

    // Q fragments direct from global (per-lane 2x16B, once), prescaled by 1/8
    f16x8 qfrag[2];
    {
        const unsigned short* qg = &qk[(size_t)(b * kL + qg_row) * (2 * kC) + h * kDH];
        #pragma unroll
        for (int kf = 0; kf < 2; ++kf) {
            f16x8 v = *reinterpret_cast<const f16x8*>(&qg[(kf * 4 + g) * 8]);
            #pragma unroll
            for (int i = 0; i < 8; ++i) v[i] *= (_Float16)0.125f;
            qfrag[kf] = v;
        }
    }

    // staging geometry: row sr = tid>>2, slots ss and ss+4
    const int sr = tid >> 2;
    const int ss = tid & 3;
    const unsigned short* kbase = &qk[(size_t)(b * kL) * (2 * kC) + kC + h * kDH];
    const unsigned short* vbase = &vt[(size_t)(b * kH + h) * kDH * kL];

    // prologue: prefetch tile 0 into registers
    f16x8 kc0 = *reinterpret_cast<const f16x8*>(&kbase[(size_t)sr * (2 * kC) + ss * 8]);
    f16x8 kc1 = *reinterpret_cast<const f16x8*>(&kbase[(size_t)sr * (2 * kC) + (ss + 4) * 8]);
    f16x8 vc0 = *reinterpret_cast<const f16x8*>(&vbase[(size_t)sr * kL + ss * 8]);
    f16x8 vc1 = *reinterpret_cast<const f16x8*>(&vbase[(size_t)sr * kL + (ss + 4) * 8]);

    float m = -INFINITY, l = 0.f;
    f32x4 acc_o[4] = {};

    for (int k0 = 0; k0 <= qlo; k0 += 64) {
        // all waves finished reading the previous tile's Ks/Vts
        asm volatile("s_waitcnt lgkmcnt(0)" ::: "memory");
        __builtin_amdgcn_sched_barrier(0);
        __builtin_amdgcn_s_barrier();
        __builtin_amdgcn_sched_barrier(0);

        // write current-tile regs -> LDS (compiler waits vmcnt for the regs)
        *reinterpret_cast<f16x8*>(&Ks[swz(sr, ss)])      = kc0;
        *reinterpret_cast<f16x8*>(&Ks[swz(sr, ss + 4)])  = kc1;
        *reinterpret_cast<f16x8*>(&Vts[swz(sr, ss)])     = vc0;
        *reinterpret_cast<f16x8*>(&Vts[swz(sr, ss + 4)]) = vc1;

        // T14: issue next-tile prefetch NOW; stays in flight across the raw
        // barrier and completes under the compute below.
        if (k0 + 64 <= qlo) {
            kc0 = *reinterpret_cast<const f16x8*>(&kbase[(size_t)(k0 + 64 + sr) * (2 * kC) + ss * 8]);
            kc1 = *reinterpret_cast<const f16x8*>(&kbase[(size_t)(k0 + 64 + sr) * (2 * kC) + (ss + 4) * 8]);
            vc0 = *reinterpret_cast<const f16x8*>(&vbase[(size_t)sr * kL + k0 + 64 + ss * 8]);
            vc1 = *reinterpret_cast<const f16x8*>(&vbase[(size_t)sr * kL + k0 + 64 + (ss + 4) * 8]);
        }

        // my LDS writes landed; barrier makes them visible to all waves
        asm volatile("s_waitcnt lgkmcnt(0)" ::: "memory");
        __builtin_amdgcn_sched_barrier(0);
        __builtin_amdgcn_s_barrier();
        __builtin_amdgcn_sched_barrier(0);

        // QK^T (swapped): acc_s[n] = D[key][q]
        f32x4 acc_s[4] = {};
        #pragma unroll
        for (int kf = 0; kf < 2; ++kf) {
            #pragma unroll
            for (int n = 0; n < 4; ++n) {
                const f16x8 kfr = *reinterpret_cast<const f16x8*>(&Ks[swz(n * 16 + fr, kf * 4 + g)]);
                acc_s[n] = __builtin_amdgcn_mfma_f32_16x16x32_f16(kfr, qfrag[kf], acc_s[n], 0, 0, 0);
            }
        }

        if (k0 == qlo) {
            #pragma unroll
            for (int n = 0; n < 4; ++n)
                #pragma unroll
                for (int j = 0; j < 4; ++j)
                    if (k0 + n * 16 + g * 4 + j > qg_row) acc_s[n][j] = -INFINITY;
        }

        float mx = -INFINITY;
        #pragma unroll
        for (int n = 0; n < 4; ++n)
            #pragma unroll
            for (int j = 0; j < 4; ++j) mx = fmaxf(mx, acc_s[n][j]);
        mx = fmaxf(mx, __shfl_xor(mx, 16));
        mx = fmaxf(mx, __shfl_xor(mx, 32));
        const float mn  = fmaxf(m, mx);
        const float fac = __expf(m - mn);
        float p[4][4];
        float psum = 0.f;
        #pragma unroll
        for (int n = 0; n < 4; ++n)
            #pragma unroll
            for (int j = 0; j < 4; ++j) { p[n][j] = __expf(acc_s[n][j] - mn); psum += p[n][j]; }
        psum += __shfl_xor(psum, 16);
        psum += __shfl_xor(psum, 32);
        l = l * fac + psum;
        m = mn;
        #pragma unroll
        for (int dt = 0; dt < 4; ++dt)
            #pragma unroll
            for (int j = 0; j < 4; ++j) acc_o[dt][j] *= fac;

        // P -> LDS f16 (wave-private rows; same-wave in-order DS)
        #pragma unroll
        for (int n = 0; n < 4; ++n) {
            f16x4 pk;
            #pragma unroll
            for (int j = 0; j < 4; ++j) pk[j] = (_Float16)p[n][j];
            *reinterpret_cast<f16x4*>(&Ps[swz(wv * 16 + fr, 2 * n + (g >> 1)) + (g & 1) * 4]) = pk;
        }

        // PV
        #pragma unroll
        for (int kf = 0; kf < 2; ++kf) {
            const f16x8 pf = *reinterpret_cast<const f16x8*>(&Ps[swz(wv * 16 + fr, kf * 4 + g)]);
            #pragma unroll
            for (int dt = 0; dt < 4; ++dt) {
                const f16x8 vf = *reinterpret_cast<const f16x8*>(&Vts[swz(dt * 16 + fr, kf * 4 + g)]);
                acc_o[dt] = __builtin_amdgcn_mfma_f32_16x16x32_f16(vf, pf, acc_o[dt], 0, 0, 0);
            }
        }
    }

    const float rl = 1.f / l;
    unsigned short* ob = &o[(size_t)(b * kL + qg_row) * kC + h * kDH];
    #pragma unroll
    for (int dt = 0; dt < 4; ++dt) {
        f16x4 pk;
        #pragma unroll
        for (int j = 0; j < 4; ++j) pk[j] = (_Float16)(acc_o[dt][j] * rl);
        *reinterpret_cast<f16x4*>(&ob[dt * 16 + g * 4]) = pk;
    }
}

// ---------------------------------------------------------------------------
extern "C" void kernel_launch(void* const* d_in, const int* in_sizes, int n_in,
                              void* d_out, int out_size, void* d_ws, size_t ws_size,
                              hipStream_t stream)
{
    (void)in_sizes; (void)n_in; (void)out_size; (void)ws_size;
    const float* obs    = (const float*)d_in[0];
    const float* act    = (const float*)d_in[1];
    const float* rew    = (const float*)d_in[2];
    const float* obs_W  = (const float*)d_in[3];
    const float* obs_b  = (const float*)d_in[4];
    const float* act_W  = (const float*)d_in[5];
    const float* act_b  = (const float*)d_in[6];
    const float* rew_W  = (const float*)d_in[7];
    const float* rew_b  = (const float*)d_in[8];
    const float* tr_W   = (const float*)d_in[9];
    const float* tr_b   = (const float*)d_in[10];
    const float* bn_g   = (const float*)d_in[11];
    const float* bn_b   = (const float*)d_in[12];
    const float* ln1_w  = (const float*)d_in[13];
    const float* ln1_b  = (const float*)d_in[14];
    const float* qkv_W  = (const float*)d_in[15];
    const float* qkv_b  = (const float*)d_in[16];
    const float* out_W  = (const float*)d_in[17];
    const float* out_b  = (const float*)d_in[18];
    const float* ln2_w  = (const float*)d_in[19];
    const float* ln2_b  = (const float*)d_in[20];
    const float* fc_W   = (const float*)d_in[21];
    const float* fc_b   = (const float*)d_in[22];
    const float* pj_W   = (const float*)d_in[23];
    const float* pj_b   = (const float*)d_in[24];

    float* x  = (float*)d_out;                     // fp32 residual stream
    float* ws = (float*)d_ws;
    float* tm   = ws;                              // 64
    float* tv   = ws + 64;                         // 64
    unsigned short* wbuf  = (unsigned short*)(ws + 128);  // 12.58M f16 weights
    unsigned short* h_hf  = wbuf + 12582912;       // 2048*1024
    unsigned short* ao_hf = h_hf + (size_t)kRows * kC;    // 2048*1024
    unsigned short* ff_hf = ao_hf + (size_t)kRows * kC;   // 2048*4096
    unsigned short* qk_hf = ff_hf + (size_t)kRows * kFF;  // 2048*2048
    unsigned short* vt_hf = qk_hf + (size_t)kRows * 2 * kC; // 2*16*64*1024
    // split-K partials: 4 x [2048][1024] f16 = 8.39M ushorts, aliased over
    // qk_hf (4.19M) + vt_hf (2.10M) + 2.10M extension (qk/vt dead after attn)
    unsigned short* part  = qk_hf;
    unsigned short* qWT = wbuf;                    // [3072][1024]
    unsigned short* oWT = qWT + 3 * kC * kC;       // [1024][1024]
    unsigned short* fWT = oWT + kC * kC;           // [4096][1024]
    unsigned short* pWT = fWT + kC * kFF;          // [1024][4096]

    tran_stats_kernel<<<kOBS, 256, 0, stream>>>(obs, tm, tv);
    encode_kernel<<<kRows, 256, 0, stream>>>(obs, act, rew,
        obs_W, obs_b, act_W, act_b, rew_W, rew_b, tr_W, tr_b, bn_g, bn_b, tm, tv, x);
    // layer-0 ln1 (subsequent ln1/ln2 are fused into reduce_ln)
    ln_kernel<<<kRows, 256, 0, stream>>>(x, ln1_w, ln1_b, h_hf);

    for (int lyr = 0; lyr < kNL; ++lyr) {
        const float* qW = qkv_W + (size_t)lyr * kC * 3 * kC;
        const float* qB = qkv_b + (size_t)lyr * 3 * kC;
        const float* oW = out_W + (size_t)lyr * kC * kC;
        const float* oB = out_b + (size_t)lyr * kC;
        const float* fW = fc_W + (size_t)lyr * kC * kFF;
        const float* fB = fc_b + (size_t)lyr * kFF;
        const float* pW = pj_W + (size_t)lyr * kFF * kC;
        const float* pB = pj_b + (size_t)lyr * kC;

        convert_layer_kernel<<<3072, 256, 0, stream>>>(
            qW, oW, fW, pW, qWT, oWT, fWT, pWT);

        gemm_f16_kernel<0,0,2><<<dim3(3 * kC / 128, kRows / 128), 256, 0, stream>>>(
            h_hf, qWT, qB, nullptr, qk_hf, vt_hf, kRows, 3 * kC, kC);
        attn_mfma_kernel<<<dim3(512), 256, 0, stream>>>(qk_hf, vt_hf, ao_hf);
        // out projection: split-K=4, f16 partials (overwrites dead qk/vt)
        gemm_f16_kernel<0,0,5><<<dim3(kC / 128, kRows / 128, 4), 256, 0, stream>>>(
            ao_hf, oWT, oB, nullptr, part, nullptr, kRows, kC, kC);
        // fused: x += sum(part); h = LN2(x)
        reduce_ln_kernel<<<kRows, 256, 0, stream>>>(
            part, ln2_w + lyr * kC, ln2_b + lyr * kC, x, h_hf);
        gemm_f16_kernel<1,0,1><<<dim3(kFF / 128, kRows / 128), 256, 0, stream>>>(
            h_hf, fWT, fB, nullptr, ff_hf, nullptr, kRows, kFF, kC);
        // pj projection: split-K=4, f16 partials
        gemm_f16_kernel<0,0,5><<<dim3(kC / 128, kRows / 128, 4), 256, 0, stream>>>(
            ff_hf, pWT, pB, nullptr, part, nullptr, kRows, kC, kFF);
        if (lyr < kNL - 1) {
            // fused: x += sum(part); h = LN1[lyr+1](x)
            reduce_ln_kernel<<<kRows, 256, 0, stream>>>(
                part, ln1_w + (lyr + 1) * kC, ln1_b + (lyr + 1) * kC, x, h_hf);
        } else {
            // fused: x += sum(part); x = tanh(x)
            reduce_tanh_kernel<<<kRows * kC / 1024, 256, 0, stream>>>(part, x);
        }
    }
}